// Round 5
// baseline (159.616 us; speedup 1.0000x reference)
//
#include <hip/hip_runtime.h>
#include <stdint.h>

#define NCHUNK 9
#define IN_DIM 128
#define OUT_DIM 128
#define NUM_F 8
#define B_TOTAL 131072

#define WBASE_ELEMS (OUT_DIM * IN_DIM)            // 16384 ushorts (chunk 0)
#define WSIN_ELEMS (8 * OUT_DIM * IN_DIM)         // 131072 ushorts (chunks 1..8)
#define UNIT 8192                                 // ushorts per stage unit (16 KB)

typedef _Float16 hf16x8 __attribute__((ext_vector_type(8)));
typedef float floatx16 __attribute__((ext_vector_type(16)));

typedef __attribute__((address_space(1))) const unsigned int gas_u32;
typedef __attribute__((address_space(3))) unsigned int las_u32;

__device__ __forceinline__ unsigned short f2h_rn(float f) {
  _Float16 h = (_Float16)f;        // v_cvt_f16_f32, RTNE
  return __builtin_bit_cast(unsigned short, h);
}

// ---------------- prep: fold coef/scale into f16 weights + bias ----------
// Wbase layout (chunk 0):  idx = ((i>>4)*2 + q2)*1024 + o*8 + j
// Wsin layout (chunks1-8): idx = ((i>>4)*16 + f*2 + q2)*1024 + o*8 + j
//   -> unit U = p*2+u (chunks 1-4 / 5-8 of phase p) = 8192 ushorts contiguous
//   (i = k index; q2=(i>>3)&1, j=i&7; phase p = i>>4)
__global__ void skan_prep(const float* __restrict__ base_w,
                          const float* __restrict__ scale_sp,
                          const float* __restrict__ coef,
                          const float* __restrict__ conv_w,
                          const float* __restrict__ conv_b,
                          unsigned short* __restrict__ Wbase,
                          unsigned short* __restrict__ Wsin,
                          float* __restrict__ bias) {
  int b = blockIdx.x;
  int i = threadIdx.x;                       // 0..127
  int j = i & 7, q2 = (i >> 3) & 1;
  if (b < NCHUNK * OUT_DIM) {
    int c = b >> 7;                          // chunk 0..8
    int o = b & 127;
    if (c == 0) {
      float v = base_w[o * IN_DIM + i];
      Wbase[((i >> 4) * 2 + q2) * 1024 + o * 8 + j] = f2h_rn(v);
    } else {
      int f = c - 1;
      float v = conv_w[(f * OUT_DIM + o) * IN_DIM + i] * coef[i * NUM_F + f] * scale_sp[o];
      Wsin[((i >> 4) * 16 + f * 2 + q2) * 1024 + o * 8 + j] = f2h_rn(v);
    }
  } else {
    float s = 0.f;
#pragma unroll
    for (int f = 0; f < NUM_F; ++f) s += conv_b[f * OUT_DIM + i];
    bias[i] = s * scale_sp[i];
  }
}

// ---------------- main ----------------
__device__ __forceinline__ hf16x8 hpack(const float* v) {
  union { unsigned u[4]; hf16x8 f; } r;
  r.u[0] = __builtin_bit_cast(unsigned, __builtin_amdgcn_cvt_pkrtz(v[0], v[1]));
  r.u[1] = __builtin_bit_cast(unsigned, __builtin_amdgcn_cvt_pkrtz(v[2], v[3]));
  r.u[2] = __builtin_bit_cast(unsigned, __builtin_amdgcn_cvt_pkrtz(v[4], v[5]));
  r.u[3] = __builtin_bit_cast(unsigned, __builtin_amdgcn_cvt_pkrtz(v[6], v[7]));
  return r.f;
}

__device__ __forceinline__ float silu(float v) {
  return v * __builtin_amdgcn_rcpf(1.f + __expf(-v));
}

// Wave tile: 32 rows x 128 cols (acc[4] = 64 AGPR). Block = 4 waves = 128 rows.
// Double-buffered 2x16KB unit staging, counted vmcnt + RAW s_barrier (no full
// drains in the main loop: T3+T4). 32 KB LDS + ~135 unified regs -> 3 blocks/CU.
__global__ __launch_bounds__(256, 3)
void skan_main(const float* __restrict__ x,
               const unsigned short* __restrict__ Wbase,
               const unsigned short* __restrict__ Wsin,
               const float* __restrict__ bias,
               float* __restrict__ out) {
  __shared__ unsigned short sB[2][UNIT];           // 2 x 16 KB

  const int tid  = threadIdx.x;
  const int lane = tid & 63;
  const int w    = tid >> 6;          // wave 0..3
  const int m    = lane & 31;
  const int q2   = lane >> 5;         // k-octet parity
  const int waveRow = blockIdx.x * 128 + w * 32;   // wave: 32 rows x 128 cols

  const int colOff = m * 8;           // per-lane col part of B-frag addr (ushorts)

  floatx16 acc[4];
#pragma unroll
  for (int nt = 0; nt < 4; ++nt)
#pragma unroll
    for (int e = 0; e < 16; ++e) acc[nt][e] = 0.f;

  const float* xr = x + (size_t)(waveRow + m) * IN_DIM;

  // stage helper: one 16 KB unit -> sB[U&1]
  auto stage_unit = [&](int U) {
    const char* src = (const char*)(Wsin + (size_t)U * UNIT);
    char* dst = (char*)&sB[U & 1][0];
    int off = tid * 16;
#pragma unroll
    for (int it = 0; it < 4; ++it) {   // 256 thr * 16B * 4 = 16 KB
      __builtin_amdgcn_global_load_lds((gas_u32*)(src + off), (las_u32*)(dst + off),
                                       16, 0, 0);
      off += 4096;
    }
  };

  // prologue: stage unit 0 (phase 0, chunks 1..4) into sB[0]
  stage_unit(0);

#pragma unroll 1
  for (int p = 0; p < 8; ++p) {       // phase p; k in [p*16, p*16+16)
    // ---- register loads for this phase (x + Wbase), issued BEFORE the wait
    //      so they are the 6 newest vmem ops at the counted wait below ----
    float xv[8];
    {
      float4 a = *(const float4*)(xr + p * 16 + q2 * 8);
      float4 b = *(const float4*)(xr + p * 16 + q2 * 8 + 4);
      xv[0] = a.x; xv[1] = a.y; xv[2] = a.z; xv[3] = a.w;
      xv[4] = b.x; xv[5] = b.y; xv[6] = b.z; xv[7] = b.w;
    }
    int4 Bb[4];
#pragma unroll
    for (int nt = 0; nt < 4; ++nt)
      Bb[nt] = *(const int4*)(Wbase + (p * 2 + q2) * 1024 + colOff + nt * 256);

    // ---- own stage(2p) retired (all but newest 6 = x2+wb4); all-waves sync.
    //      RAW barrier: no vmcnt(0)/lgkmcnt(0) drain. ----
    asm volatile("s_waitcnt vmcnt(6)" ::: "memory");
    __builtin_amdgcn_s_barrier();
    __builtin_amdgcn_sched_barrier(0);
    // ---- issue prefetch of unit 2p+1 (chunks 5..8) -> sB[1] ----
    stage_unit(2 * p + 1);
    __builtin_amdgcn_sched_barrier(0);

    // ---- chunk 0 (silu, B from global/L2). Compiler's wait for Bb is
    //      vmcnt(4): leaves the 4 just-issued staging loads in flight. ----
    {
      float sv[8];
#pragma unroll
      for (int j = 0; j < 8; ++j) sv[j] = silu(xv[j]);
      hf16x8 a0 = hpack(sv);
      __builtin_amdgcn_s_setprio(1);
#pragma unroll
      for (int nt = 0; nt < 4; ++nt) {
        hf16x8 bf = __builtin_bit_cast(hf16x8, Bb[nt]);
        acc[nt] = __builtin_amdgcn_mfma_f32_32x32x16_f16(a0, bf, acc[nt], 0, 0, 0);
      }
      __builtin_amdgcn_s_setprio(0);
    }

    // ---- recurrence init ----
    float sp[8], spp[8], c2[8];
#pragma unroll
    for (int j = 0; j < 8; ++j) {
      float xx = xv[j];
      sp[j]  = __sinf(xx);
      c2[j]  = 2.f * __cosf(xx);
      spp[j] = 0.f;
    }

    // ---- unit u=0: chunks 1..4 from sB[0] ----
#pragma unroll
    for (int cc = 0; cc < 4; ++cc) {   // c = cc+1
      hf16x8 Bf[4];
      const unsigned short* bp = &sB[0][(cc * 2 + q2) * 1024 + colOff];
#pragma unroll
      for (int nt = 0; nt < 4; ++nt)
        Bf[nt] = *(const hf16x8*)(bp + nt * 256);
      if (cc >= 1) {
#pragma unroll
        for (int j = 0; j < 8; ++j) {
          float t = __builtin_fmaf(c2[j], sp[j], -spp[j]);
          spp[j] = sp[j];
          sp[j] = t;
        }
      }
      hf16x8 a0 = hpack(sp);
      __builtin_amdgcn_s_setprio(1);
#pragma unroll
      for (int nt = 0; nt < 4; ++nt)
        acc[nt] = __builtin_amdgcn_mfma_f32_32x32x16_f16(a0, Bf[nt], acc[nt], 0, 0, 0);
      __builtin_amdgcn_s_setprio(0);
    }

    // ---- unit u=1: wait own stage(2p+1) (nothing younger in flight),
    //      raw barrier, prefetch unit 2p+2 -> sB[0], compute chunks 5..8 ----
    asm volatile("s_waitcnt vmcnt(0)" ::: "memory");
    __builtin_amdgcn_s_barrier();
    __builtin_amdgcn_sched_barrier(0);
    if (p < 7) stage_unit(2 * p + 2);
    __builtin_amdgcn_sched_barrier(0);

#pragma unroll
    for (int cc = 0; cc < 4; ++cc) {   // c = cc+5
      hf16x8 Bf[4];
      const unsigned short* bp = &sB[1][(cc * 2 + q2) * 1024 + colOff];
#pragma unroll
      for (int nt = 0; nt < 4; ++nt)
        Bf[nt] = *(const hf16x8*)(bp + nt * 256);
#pragma unroll
      for (int j = 0; j < 8; ++j) {
        float t = __builtin_fmaf(c2[j], sp[j], -spp[j]);
        spp[j] = sp[j];
        sp[j] = t;
      }
      hf16x8 a0 = hpack(sp);
      __builtin_amdgcn_s_setprio(1);
#pragma unroll
      for (int nt = 0; nt < 4; ++nt)
        acc[nt] = __builtin_amdgcn_mfma_f32_32x32x16_f16(a0, Bf[nt], acc[nt], 0, 0, 0);
      __builtin_amdgcn_s_setprio(0);
    }
  }

  // ---- epilogue: C/D layout col=lane&31, row=(e&3)+8*(e>>2)+4*q2 ----
  float* obase = out + (size_t)waveRow * OUT_DIM + m;
#pragma unroll
  for (int nt = 0; nt < 4; ++nt) {
    float bv = bias[nt * 32 + m];
#pragma unroll
    for (int e = 0; e < 16; ++e) {
      int rl = (e & 3) + 8 * (e >> 2) + 4 * q2;
      obase[(size_t)rl * OUT_DIM + nt * 32] = acc[nt][e] + bv;
    }
  }
}

extern "C" void kernel_launch(void* const* d_in, const int* in_sizes, int n_in,
                              void* d_out, int out_size, void* d_ws, size_t ws_size,
                              hipStream_t stream) {
  const float* x      = (const float*)d_in[0];
  // d_in[1] = grid — exactly [1..8]; encoded via Chebyshev recurrence
  const float* base_w = (const float*)d_in[2];
  const float* scale  = (const float*)d_in[3];
  const float* coef   = (const float*)d_in[4];
  const float* conv_w = (const float*)d_in[5];
  const float* conv_b = (const float*)d_in[6];

  unsigned short* Wbase = (unsigned short*)d_ws;
  unsigned short* Wsin  = Wbase + WBASE_ELEMS;
  float* bias = (float*)(Wsin + WSIN_ELEMS);
  float* out  = (float*)d_out;

  // prep must run every launch: d_ws is re-poisoned before each timed call
  skan_prep<<<NCHUNK * OUT_DIM + 1, 128, 0, stream>>>(base_w, scale, coef,
                                                      conv_w, conv_b, Wbase, Wsin, bias);
  skan_main<<<B_TOTAL / 128, 256, 0, stream>>>(x, Wbase, Wsin, bias, out);
}

// Round 6
// 150.931 us; speedup vs baseline: 1.0575x; 1.0575x over previous
//
#include <hip/hip_runtime.h>
#include <stdint.h>

#define NCHUNK 9
#define IN_DIM 128
#define OUT_DIM 128
#define NUM_F 8
#define B_TOTAL 131072

#define WBASE_ELEMS (OUT_DIM * IN_DIM)            // 16384 ushorts (chunk 0)
#define WSIN_ELEMS (8 * OUT_DIM * IN_DIM)         // 131072 ushorts (chunks 1..8)
#define HALF_ELEMS 65536                          // ushorts per k-half (128 KB)

typedef _Float16 hf16x8 __attribute__((ext_vector_type(8)));
typedef float floatx16 __attribute__((ext_vector_type(16)));

typedef __attribute__((address_space(1))) const unsigned int gas_u32;
typedef __attribute__((address_space(3))) unsigned int las_u32;

__device__ __forceinline__ unsigned short f2h_rn(float f) {
  _Float16 h = (_Float16)f;        // v_cvt_f16_f32, RTNE
  return __builtin_bit_cast(unsigned short, h);
}

// ---------------- prep: fold coef/scale into f16 weights + bias ----------
// Wbase layout (chunk 0):  idx = ((i>>4)*2 + q2)*1024 + o*8 + j
// Wsin layout (chunks1-8): idx = ((i>>4)*16 + f*2 + q2)*1024 + o*8 + j
//   phase p = i>>4; k-half kh = i>>6. Each k-half = 65536 ushorts (128 KB)
//   contiguous -> staged to LDS as-is.
__global__ void skan_prep(const float* __restrict__ base_w,
                          const float* __restrict__ scale_sp,
                          const float* __restrict__ coef,
                          const float* __restrict__ conv_w,
                          const float* __restrict__ conv_b,
                          unsigned short* __restrict__ Wbase,
                          unsigned short* __restrict__ Wsin,
                          float* __restrict__ bias) {
  int b = blockIdx.x;
  int i = threadIdx.x;                       // 0..127
  int j = i & 7, q2 = (i >> 3) & 1;
  if (b < NCHUNK * OUT_DIM) {
    int c = b >> 7;                          // chunk 0..8
    int o = b & 127;
    if (c == 0) {
      float v = base_w[o * IN_DIM + i];
      Wbase[((i >> 4) * 2 + q2) * 1024 + o * 8 + j] = f2h_rn(v);
    } else {
      int f = c - 1;
      float v = conv_w[(f * OUT_DIM + o) * IN_DIM + i] * coef[i * NUM_F + f] * scale_sp[o];
      Wsin[((i >> 4) * 16 + f * 2 + q2) * 1024 + o * 8 + j] = f2h_rn(v);
    }
  } else {
    float s = 0.f;
#pragma unroll
    for (int f = 0; f < NUM_F; ++f) s += conv_b[f * OUT_DIM + i];
    bias[i] = s * scale_sp[i];
  }
}

// ---------------- main ----------------
__device__ __forceinline__ hf16x8 hpack(const float* v) {
  union { unsigned u[4]; hf16x8 f; } r;
  r.u[0] = __builtin_bit_cast(unsigned, __builtin_amdgcn_cvt_pkrtz(v[0], v[1]));
  r.u[1] = __builtin_bit_cast(unsigned, __builtin_amdgcn_cvt_pkrtz(v[2], v[3]));
  r.u[2] = __builtin_bit_cast(unsigned, __builtin_amdgcn_cvt_pkrtz(v[4], v[5]));
  r.u[3] = __builtin_bit_cast(unsigned, __builtin_amdgcn_cvt_pkrtz(v[6], v[7]));
  return r.f;
}

__device__ __forceinline__ float silu(float v) {
  return v * __builtin_amdgcn_rcpf(1.f + __expf(-v));
}

// Free-running design: 1 block/CU (512 thr = 8 fat waves of 64 rows x 128 cols,
// grid 256). 128 KB dynamic LDS = one full k-half of Wsin (chunks 1..8), staged
// twice; only 3 barriers in the whole kernel. Between barriers the 8 waves run
// 4 phases x 9 chunks with zero sync -> natural desync -> MFMA/VALU/LDS/L2
// pipes overlap across waves. acc[2][4]=128 AGPR + ~128 VGPR -> 2 waves/SIMD.
__global__ __launch_bounds__(512, 2)
void skan_main(const float* __restrict__ x,
               const unsigned short* __restrict__ Wbase,
               const unsigned short* __restrict__ Wsin,
               const float* __restrict__ bias,
               float* __restrict__ out) {
  extern __shared__ unsigned short sB[];           // 65536 ushorts = 128 KB

  const int tid  = threadIdx.x;
  const int lane = tid & 63;
  const int w    = tid >> 6;          // wave 0..7
  const int m    = lane & 31;
  const int q2   = lane >> 5;         // k-octet parity
  const int rowBase = blockIdx.x * 512 + w * 64;   // wave: 64 rows x 128 cols

  const int colOff = m * 8;           // per-lane col part of B-frag addr (ushorts)

  floatx16 acc[2][4];
#pragma unroll
  for (int mt = 0; mt < 2; ++mt)
#pragma unroll
    for (int nt = 0; nt < 4; ++nt)
#pragma unroll
      for (int e = 0; e < 16; ++e) acc[mt][nt][e] = 0.f;

  const float* xr0 = x + (size_t)(rowBase + m) * IN_DIM;
  const float* xr1 = xr0 + 32 * IN_DIM;

#pragma unroll 1
  for (int kh = 0; kh < 2; ++kh) {    // k-half: k in [kh*64, kh*64+64)
    if (kh) __syncthreads();          // all waves done reading half 0

    // ---- stage this k-half's 128 KB (chunks 1..8) ----
    {
      const char* src = (const char*)(Wsin + kh * HALF_ELEMS);
      char* dst = (char*)sB;
      int off = tid * 16;
#pragma unroll
      for (int it = 0; it < 16; ++it) {   // 512 thr * 16B * 16 = 128 KB
        __builtin_amdgcn_global_load_lds((gas_u32*)(src + off), (las_u32*)(dst + off),
                                         16, 0, 0);
        off += 8192;
      }
    }

#pragma unroll
    for (int ph = 0; ph < 4; ++ph) {  // phase p = kh*4+ph; k in [p*16, p*16+16)
      const int p = kh * 4 + ph;

      // ---- x slice: xv[mt][j], k = p*16 + q2*8 + j ----
      float xv[2][8];
#pragma unroll
      for (int mt = 0; mt < 2; ++mt) {
        const float* xr = mt ? xr1 : xr0;
        float4 a = *(const float4*)(xr + p * 16 + q2 * 8);
        float4 b = *(const float4*)(xr + p * 16 + q2 * 8 + 4);
        xv[mt][0] = a.x; xv[mt][1] = a.y; xv[mt][2] = a.z; xv[mt][3] = a.w;
        xv[mt][4] = b.x; xv[mt][5] = b.y; xv[mt][6] = b.z; xv[mt][7] = b.w;
      }

      // ---- issue Wbase (chunk 0) loads now; consumed LAST in this phase,
      //      so L2 latency hides under the 8 LDS chunks ----
      int4 Bb[4];
#pragma unroll
      for (int nt = 0; nt < 4; ++nt)
        Bb[nt] = *(const int4*)(Wbase + (p * 2 + q2) * 1024 + colOff + nt * 256);

      // ---- recurrence init ----
      float sp[16], spp[16], c2[16];
#pragma unroll
      for (int mt = 0; mt < 2; ++mt)
#pragma unroll
        for (int j = 0; j < 8; ++j) {
          int v = mt * 8 + j;
          float xx = xv[mt][j];
          sp[v]  = __sinf(xx);
          c2[v]  = 2.f * __cosf(xx);
          spp[v] = 0.f;
        }

      if (ph == 0) __syncthreads();   // staged half visible (once per kh)

      // ---- chunks 1..8 from LDS ----
#pragma unroll
      for (int c = 1; c <= 8; ++c) {
        hf16x8 Bf[4];
        const unsigned short* bp = sB + (ph * 16 + (c - 1) * 2 + q2) * 1024 + colOff;
#pragma unroll
        for (int nt = 0; nt < 4; ++nt)
          Bf[nt] = *(const hf16x8*)(bp + nt * 256);

        if (c >= 2) {
#pragma unroll
          for (int v = 0; v < 16; ++v) {
            float t = __builtin_fmaf(c2[v], sp[v], -spp[v]);
            spp[v] = sp[v];
            sp[v] = t;
          }
        }
        hf16x8 a0 = hpack(&sp[0]);
        hf16x8 a1 = hpack(&sp[8]);
#pragma unroll
        for (int nt = 0; nt < 4; ++nt) {
          acc[0][nt] = __builtin_amdgcn_mfma_f32_32x32x16_f16(a0, Bf[nt], acc[0][nt], 0, 0, 0);
          acc[1][nt] = __builtin_amdgcn_mfma_f32_32x32x16_f16(a1, Bf[nt], acc[1][nt], 0, 0, 0);
        }
      }

      // ---- chunk 0 (silu), Bb now long-since arrived ----
      {
        float sv[16];
#pragma unroll
        for (int mt = 0; mt < 2; ++mt)
#pragma unroll
          for (int j = 0; j < 8; ++j) sv[mt * 8 + j] = silu(xv[mt][j]);
        hf16x8 a0 = hpack(&sv[0]);
        hf16x8 a1 = hpack(&sv[8]);
#pragma unroll
        for (int nt = 0; nt < 4; ++nt) {
          hf16x8 bf = __builtin_bit_cast(hf16x8, Bb[nt]);
          acc[0][nt] = __builtin_amdgcn_mfma_f32_32x32x16_f16(a0, bf, acc[0][nt], 0, 0, 0);
          acc[1][nt] = __builtin_amdgcn_mfma_f32_32x32x16_f16(a1, bf, acc[1][nt], 0, 0, 0);
        }
      }
    }
  }

  // ---- epilogue: C/D layout col=lane&31, row=(e&3)+8*(e>>2)+4*q2 ----
#pragma unroll
  for (int mt = 0; mt < 2; ++mt) {
    float* obase = out + (size_t)(rowBase + mt * 32) * OUT_DIM + m;
#pragma unroll
    for (int nt = 0; nt < 4; ++nt) {
      float bv = bias[nt * 32 + m];
#pragma unroll
      for (int e = 0; e < 16; ++e) {
        int rl = (e & 3) + 8 * (e >> 2) + 4 * q2;
        obase[(size_t)rl * OUT_DIM + nt * 32] = acc[mt][nt][e] + bv;
      }
    }
  }
}

extern "C" void kernel_launch(void* const* d_in, const int* in_sizes, int n_in,
                              void* d_out, int out_size, void* d_ws, size_t ws_size,
                              hipStream_t stream) {
  const float* x      = (const float*)d_in[0];
  // d_in[1] = grid — exactly [1..8]; encoded via Chebyshev recurrence
  const float* base_w = (const float*)d_in[2];
  const float* scale  = (const float*)d_in[3];
  const float* coef   = (const float*)d_in[4];
  const float* conv_w = (const float*)d_in[5];
  const float* conv_b = (const float*)d_in[6];

  unsigned short* Wbase = (unsigned short*)d_ws;
  unsigned short* Wsin  = Wbase + WBASE_ELEMS;
  float* bias = (float*)(Wsin + WSIN_ELEMS);
  float* out  = (float*)d_out;

  // opt-in for 128 KB dynamic LDS (host-side module op; not a stream op,
  // executes immediately even under graph capture)
  static bool attr_done = false;
  if (!attr_done) {
    hipFuncSetAttribute((const void*)skan_main,
                        hipFuncAttributeMaxDynamicSharedMemorySize,
                        HALF_ELEMS * 2);
    attr_done = true;
  }

  // prep must run every launch: d_ws is re-poisoned before each timed call
  skan_prep<<<NCHUNK * OUT_DIM + 1, 128, 0, stream>>>(base_w, scale, coef,
                                                      conv_w, conv_b, Wbase, Wsin, bias);
  skan_main<<<B_TOTAL / 512, 512, HALF_ELEMS * 2, stream>>>(x, Wbase, Wsin, bias, out);
}